// Round 10
// baseline (244.994 us; speedup 1.0000x reference)
//
#include <hip/hip_runtime.h>
#include <hip/hip_fp16.h>

// DAS beamforming: out[b,z,x,k] = sum_c lerp(rf[b,c], delay(b,c,z,x))[k]
// Round 15: R10 skeleton + FUSED last-block reduction (one das dispatch).
//  Geometry sweep closed: staging/partials (64/33.6, 134/16.8, 268/8.4) MB
//  gave totals 93.6 / 87.0 / 91.8 -> R10's 134/16.8 is the parabola bottom.
//  das < 41 us in every healthy config (never tops the 41-us poison fills in
//  the profile); residual addressable time is the reduce dispatch + its
//  launch gap (~5-6 us). Fuse it: each block stores partials (PLAIN stores -
//  NT dropped: cross-XCD visibility under threadfence uncertain; R5 proved
//  plain 16.8 MB healthy), then the canonical threadfence-reduction pattern:
//    stores -> __threadfence() (release: L2 writeback) -> __syncthreads()
//    -> t0 atomicAdd(cnt[b][tile]) -> 8th arrival does __threadfence()
//    (acquire: invalidates stale clean poison copies in its XCD L2 - G16)
//    -> reads other 7 chunks' partials -> writes out.
//  Counters (128 B in ws after partials) zeroed by a tiny memset each
//  iteration (graph-replayed). sbase hoist restored.
//  Kept: fp16 2x16KB double buffer, reg-staged cvt from CLEAN rf (never
//  read poisoned ws), T14 async split, chunk=bid&7 XCD pinning (rf 1MB/L2),
//  grid 256 = 1 block/CU, C_PER_BLOCK=16, PX=4, THREADS=1024.

#define NBATCH 2
#define NC 128
#define NS 2048
#define NK 4
#define NM 65536                              // Nz*Nx pixels per batch

#define THREADS 1024
#define PX_PER_THREAD 4
#define PX_PER_BLOCK (THREADS * PX_PER_THREAD)   // 4096
#define C_PER_BLOCK 16
#define N_CHUNKS (NC / C_PER_BLOCK)           // 8
#define N_TILES (NM / PX_PER_BLOCK)           // 16
#define NBLOCKS (NBATCH * N_TILES * N_CHUNKS) // 256 = 1 block/CU

#define PART_BYTES ((size_t)N_CHUNKS * NBATCH * NM * NK * 4)  // 16.8 MB
#define CNT_BYTES ((size_t)NBATCH * N_TILES * 4)              // 128 B

typedef float f32x4 __attribute__((ext_vector_type(4)));

// pack 8 f32 -> 8 f16 (one half4 sample pair) for LDS residency
__device__ __forceinline__ uint4 cvt8(float4 a, float4 b) {
    const __half2 h0 = __floats2half2_rn(a.x, a.y);
    const __half2 h1 = __floats2half2_rn(a.z, a.w);
    const __half2 h2 = __floats2half2_rn(b.x, b.y);
    const __half2 h3 = __floats2half2_rn(b.z, b.w);
    return make_uint4(__builtin_bit_cast(unsigned, h0),
                      __builtin_bit_cast(unsigned, h1),
                      __builtin_bit_cast(unsigned, h2),
                      __builtin_bit_cast(unsigned, h3));
}

template <bool ATOMIC>
__global__ __launch_bounds__(THREADS, 4) void das_kernel(
    const float* __restrict__ rf, const float* __restrict__ g,
    const float* __restrict__ pr, const float* __restrict__ p,
    float* __restrict__ part, unsigned* __restrict__ cnt,
    float* __restrict__ out)
{
    __shared__ uint4 sbuf[2][NS / 2];   // 2 x 16 KiB fp16 double buffer
    __shared__ int s_rank;

    const int bid   = blockIdx.x;
    const int chunk = bid & (N_CHUNKS - 1);          // bid%8 == XCD id
    const int tile  = (bid >> 3) & (N_TILES - 1);
    const int b     = bid >> 7;
    const int t     = threadIdx.x;
    const int px0   = tile * PX_PER_BLOCK;

    const float c0v = p[b * 4 + 0];
    const float fsv = p[b * 4 + 1];
    const float t0v = p[b * 4 + 2];
    const float scale = fsv / c0v;            // samples per meter
    const float sb0   = scale * t0v;

    float gx[PX_PER_THREAD], gy[PX_PER_THREAD], gzv[PX_PER_THREAD],
          sbase[PX_PER_THREAD];
#pragma unroll
    for (int j = 0; j < PX_PER_THREAD; ++j) {
        const int m = px0 + j * THREADS + t;
        const float* gp = g + ((size_t)b * NM + m) * 3;
        gx[j]  = gp[0];
        gy[j]  = gp[1];
        gzv[j] = gp[2];
        sbase[j] = fmaf(scale, gzv[j], sb0);  // fs*(t0 + d_tx)/c0 hoisted
    }

    float4 acc[PX_PER_THREAD];
#pragma unroll
    for (int j = 0; j < PX_PER_THREAD; ++j) acc[j] = make_float4(0.f, 0.f, 0.f, 0.f);

    const int ch0 = chunk * C_PER_BLOCK;
    const float* slice0 = rf + (size_t)(b * NC + ch0) * NS * NK;

    // initial stage: slice 0 -> regs -> fp16 -> buf0 (thread t owns slot t)
    {
        const float4* s4 = (const float4*)slice0;
        const float4 a0 = s4[2 * t];
        const float4 a1 = s4[2 * t + 1];
        sbuf[0][t] = cvt8(a0, a1);
    }

    for (int cc = 0; cc < C_PER_BLOCK; ++cc) {
        // barrier publishes buf (cc&1) writes from the previous iteration and
        // guarantees everyone finished reading buf ((cc+1)&1) two iters ago.
        __syncthreads();

        // T14 async split: issue next slice's global loads NOW; the vmcnt
        // drain + cvt + ds_write happen after this iteration's compute.
        float4 a0, a1;
        if (cc + 1 < C_PER_BLOCK) {
            const float4* s4 = (const float4*)(slice0 + (size_t)(cc + 1) * NS * NK);
            a0 = s4[2 * t];
            a1 = s4[2 * t + 1];
        }

        const uint2* lb = (const uint2*)&sbuf[cc & 1][0];   // half4 samples
        const float* prp = pr + ((size_t)(b * NC + ch0 + cc)) * 3;
        const float prx = prp[0], pry = prp[1], prz = prp[2];

#pragma unroll
        for (int j = 0; j < PX_PER_THREAD; ++j) {
            const float dx = gx[j]  - prx;
            const float dy = gy[j]  - pry;
            const float dz = gzv[j] - prz;
            const float drx = __builtin_amdgcn_sqrtf(fmaf(dx, dx, fmaf(dy, dy, dz * dz)));
            float s = fmaf(scale, drx, sbase[j]);          // fractional sample
            s = fminf(fmaxf(s, 0.0f), (float)(NS - 1));    // clamp
            const float fi = fminf(floorf(s), (float)(NS - 2));
            const float w  = s - fi;
            const float wm = 1.0f - w;
            const int i0 = (int)fi;
            const uint2 u0 = lb[i0];          // half4 y0 | contiguous 16 B:
            const uint2 u1 = lb[i0 + 1];      // half4 y1 | one ds_read2_b64
            const float2 y0a = __half22float2(__builtin_bit_cast(__half2, u0.x));
            const float2 y0b = __half22float2(__builtin_bit_cast(__half2, u0.y));
            const float2 y1a = __half22float2(__builtin_bit_cast(__half2, u1.x));
            const float2 y1b = __half22float2(__builtin_bit_cast(__half2, u1.y));
            acc[j].x = fmaf(y0a.x, wm, fmaf(y1a.x, w, acc[j].x));
            acc[j].y = fmaf(y0a.y, wm, fmaf(y1a.y, w, acc[j].y));
            acc[j].z = fmaf(y0b.x, wm, fmaf(y1b.x, w, acc[j].z));
            acc[j].w = fmaf(y0b.y, wm, fmaf(y1b.y, w, acc[j].w));
        }

        // drain the prefetch (s_waitcnt auto-inserted), convert, publish on
        // the NEXT barrier. Writing buf ((cc+1)&1) is safe: all waves passed
        // the barrier above, so nobody still reads it from iteration cc-1.
        if (cc + 1 < C_PER_BLOCK)
            sbuf[(cc + 1) & 1][t] = cvt8(a0, a1);
    }

    if (ATOMIC) {
        float* ob = out + (size_t)b * NM * NK;
#pragma unroll
        for (int j = 0; j < PX_PER_THREAD; ++j) {
            const int m = px0 + j * THREADS + t;
            float* op = ob + (size_t)m * NK;
            atomicAdd(op + 0, acc[j].x);
            atomicAdd(op + 1, acc[j].y);
            atomicAdd(op + 2, acc[j].z);
            atomicAdd(op + 3, acc[j].w);
        }
        return;
    }

    // ---- fused reduction: partial[chunk][b][m], plain stores (disjoint) ----
    f32x4* pw = (f32x4*)part + (size_t)(chunk * NBATCH + b) * NM;
#pragma unroll
    for (int j = 0; j < PX_PER_THREAD; ++j) {
        const int m = px0 + j * THREADS + t;
        const f32x4 v = {acc[j].x, acc[j].y, acc[j].z, acc[j].w};
        pw[m] = v;
    }

    // release: every thread flushes its own stores to the coherence point,
    // THEN the block-wide arrival is announced by one atomic (device scope).
    __threadfence();
    __syncthreads();
    if (t == 0) s_rank = (int)atomicAdd(&cnt[b * N_TILES + tile], 1u);
    __syncthreads();

    if (s_rank == N_CHUNKS - 1) {
        // acquire: invalidate this XCD's stale (clean-poison) L2 copies of
        // the other chunks' partial lines before reading them (G16).
        __threadfence();
        const f32x4* pp = (const f32x4*)part;
        f32x4* ob = (f32x4*)out + (size_t)b * NM;
#pragma unroll
        for (int j = 0; j < PX_PER_THREAD; ++j) {
            const int m = px0 + j * THREADS + t;
            f32x4 s = {acc[j].x, acc[j].y, acc[j].z, acc[j].w};  // own chunk
#pragma unroll
            for (int c = 0; c < N_CHUNKS; ++c) {
                if (c == 0 && chunk == 0) continue;   // skip own chunk slot
                if (c != chunk)
                    s += pp[(size_t)(c * NBATCH + b) * NM + m];
            }
            ob[m] = s;
        }
    }
}

extern "C" void kernel_launch(void* const* d_in, const int* in_sizes, int n_in,
                              void* d_out, int out_size, void* d_ws, size_t ws_size,
                              hipStream_t stream) {
    (void)in_sizes; (void)n_in;
    const float* rf = (const float*)d_in[0];
    const float* g  = (const float*)d_in[1];
    const float* pr = (const float*)d_in[2];
    const float* p  = (const float*)d_in[3];
    float* out = (float*)d_out;

    if (ws_size >= PART_BYTES + CNT_BYTES) {
        unsigned* cnt = (unsigned*)((char*)d_ws + PART_BYTES);
        (void)hipMemsetAsync(cnt, 0, CNT_BYTES, stream);
        das_kernel<false><<<NBLOCKS, THREADS, 0, stream>>>(
            rf, g, pr, p, (float*)d_ws, cnt, out);
    } else {
        (void)hipMemsetAsync(d_out, 0, (size_t)out_size * sizeof(float), stream);
        das_kernel<true><<<NBLOCKS, THREADS, 0, stream>>>(
            rf, g, pr, p, nullptr, nullptr, out);
    }
}

// Round 12
// 87.396 us; speedup vs baseline: 2.8033x; 2.8033x over previous
//
#include <hip/hip_runtime.h>
#include <hip/hip_fp16.h>

// DAS beamforming: out[b,z,x,k] = sum_c lerp(rf[b,c], delay(b,c,z,x))[k]
// Round 17 = Round 16 resubmitted verbatim (R16 bench was an infra failure:
// "MI355X container failed twice"; no counters produced).
//  This is the measured session optimum (R10, 86.97 us).
//  R15 post-mortem: fused last-block reduction via __threadfence() was
//  catastrophic (das 204 us, VALUBusy 6%) — device-scope release/acquire
//  fences from 256 blocks serialize through L2 writeback/invalidate on CDNA.
//  Grid-level fusion is dead; the separate reduce dispatch (~3 us) stays.
//  Session bracket: das = 38-43 us across {f32,fp16} x {1,8,16 barriers} x
//  {1,2,4 blocks/CU} x {2,16-deep MLP} x {64-268 MB staging}; geometry
//  parabola (staging/partials 64/33.6 -> 93.6, 134/16.8 -> 87.0,
//  268/8.4 -> 91.8 total) bottoms at THIS config. Window decomposition:
//  41.4 us harness ws-poison (fixed, HBM-bound) + ~38 us latency-floor das
//  + ~3 us reduce + ~4 us gaps.
//  Structure: fp16-in-LDS, on-the-fly conversion from the CLEAN rf input
//  (never read poisoned ws), 2 x 16 KiB double buffer, T14 async split,
//  256 blocks = 2 batch x 16 tiles x 8 chunks (chunk=bid&7 pins chunk<->XCD,
//  rf footprint 1 MB/L2), 1 block/CU, NT f32 partials + reduce kernel.

#define NBATCH 2
#define NC 128
#define NS 2048
#define NK 4
#define NM 65536                              // Nz*Nx pixels per batch

#define THREADS 1024
#define PX_PER_THREAD 4
#define PX_PER_BLOCK (THREADS * PX_PER_THREAD)   // 4096
#define C_PER_BLOCK 16
#define N_CHUNKS (NC / C_PER_BLOCK)           // 8
#define N_TILES (NM / PX_PER_BLOCK)           // 16
#define NBLOCKS (NBATCH * N_TILES * N_CHUNKS) // 256 = 1 block/CU

#define PART_BYTES ((size_t)N_CHUNKS * NBATCH * NM * NK * 4)  // 16.8 MB

typedef float f32x4 __attribute__((ext_vector_type(4)));

// pack 8 f32 -> 8 f16 (one half4 sample pair) for LDS residency
__device__ __forceinline__ uint4 cvt8(float4 a, float4 b) {
    const __half2 h0 = __floats2half2_rn(a.x, a.y);
    const __half2 h1 = __floats2half2_rn(a.z, a.w);
    const __half2 h2 = __floats2half2_rn(b.x, b.y);
    const __half2 h3 = __floats2half2_rn(b.z, b.w);
    return make_uint4(__builtin_bit_cast(unsigned, h0),
                      __builtin_bit_cast(unsigned, h1),
                      __builtin_bit_cast(unsigned, h2),
                      __builtin_bit_cast(unsigned, h3));
}

template <bool ATOMIC>
__global__ __launch_bounds__(THREADS, 4) void das_kernel(
    const float* __restrict__ rf, const float* __restrict__ g,
    const float* __restrict__ pr, const float* __restrict__ p,
    float* __restrict__ dst)    // ATOMIC ? out : partials in ws
{
    __shared__ uint4 sbuf[2][NS / 2];   // 2 x 16 KiB fp16 double buffer

    const int bid   = blockIdx.x;
    const int chunk = bid & (N_CHUNKS - 1);          // chunk&7 == XCD id
    const int tile  = (bid >> 3) & (N_TILES - 1);
    const int b     = bid >> 7;
    const int t     = threadIdx.x;
    const int px0   = tile * PX_PER_BLOCK;

    const float c0v = p[b * 4 + 0];
    const float fsv = p[b * 4 + 1];
    const float t0v = p[b * 4 + 2];
    const float scale = fsv / c0v;            // samples per meter
    const float sb0   = scale * t0v;

    float gx[PX_PER_THREAD], gy[PX_PER_THREAD], gzv[PX_PER_THREAD];
#pragma unroll
    for (int j = 0; j < PX_PER_THREAD; ++j) {
        const int m = px0 + j * THREADS + t;
        const float* gp = g + ((size_t)b * NM + m) * 3;
        gx[j]  = gp[0];
        gy[j]  = gp[1];
        gzv[j] = gp[2];
    }

    float4 acc[PX_PER_THREAD];
#pragma unroll
    for (int j = 0; j < PX_PER_THREAD; ++j) acc[j] = make_float4(0.f, 0.f, 0.f, 0.f);

    const int ch0 = chunk * C_PER_BLOCK;
    const float* slice0 = rf + (size_t)(b * NC + ch0) * NS * NK;

    // initial stage: slice 0 -> regs -> fp16 -> buf0 (thread t owns slot t)
    {
        const float4* s4 = (const float4*)slice0;
        const float4 a0 = s4[2 * t];
        const float4 a1 = s4[2 * t + 1];
        sbuf[0][t] = cvt8(a0, a1);
    }

    for (int cc = 0; cc < C_PER_BLOCK; ++cc) {
        // barrier publishes buf (cc&1) writes from the previous iteration and
        // guarantees everyone finished reading buf ((cc+1)&1) two iters ago.
        __syncthreads();

        // T14 async split: issue next slice's global loads NOW; the vmcnt
        // drain + cvt + ds_write happen after this iteration's compute.
        float4 a0, a1;
        if (cc + 1 < C_PER_BLOCK) {
            const float4* s4 = (const float4*)(slice0 + (size_t)(cc + 1) * NS * NK);
            a0 = s4[2 * t];
            a1 = s4[2 * t + 1];
        }

        const uint2* lb = (const uint2*)&sbuf[cc & 1][0];   // half4 samples
        const float* prp = pr + ((size_t)(b * NC + ch0 + cc)) * 3;
        const float prx = prp[0], pry = prp[1], prz = prp[2];

#pragma unroll
        for (int j = 0; j < PX_PER_THREAD; ++j) {
            const float dx = gx[j]  - prx;
            const float dy = gy[j]  - pry;
            const float dz = gzv[j] - prz;
            const float drx = __builtin_amdgcn_sqrtf(fmaf(dx, dx, fmaf(dy, dy, dz * dz)));
            float s = fmaf(scale, gzv[j] + drx, sb0);      // fs*(t0+gz+drx)/c0
            s = fminf(fmaxf(s, 0.0f), (float)(NS - 1));    // clamp
            const float fi = fminf(floorf(s), (float)(NS - 2));
            const float w  = s - fi;
            const float wm = 1.0f - w;
            const int i0 = (int)fi;
            const uint2 u0 = lb[i0];          // half4 y0 | contiguous 16 B:
            const uint2 u1 = lb[i0 + 1];      // half4 y1 | one ds_read2_b64
            const float2 y0a = __half22float2(__builtin_bit_cast(__half2, u0.x));
            const float2 y0b = __half22float2(__builtin_bit_cast(__half2, u0.y));
            const float2 y1a = __half22float2(__builtin_bit_cast(__half2, u1.x));
            const float2 y1b = __half22float2(__builtin_bit_cast(__half2, u1.y));
            acc[j].x = fmaf(y0a.x, wm, fmaf(y1a.x, w, acc[j].x));
            acc[j].y = fmaf(y0a.y, wm, fmaf(y1a.y, w, acc[j].y));
            acc[j].z = fmaf(y0b.x, wm, fmaf(y1b.x, w, acc[j].z));
            acc[j].w = fmaf(y0b.y, wm, fmaf(y1b.y, w, acc[j].w));
        }

        // drain the prefetch (s_waitcnt auto-inserted), convert, publish on
        // the NEXT barrier. Writing buf ((cc+1)&1) is safe: all waves passed
        // the barrier above, so nobody still reads it from iteration cc-1.
        if (cc + 1 < C_PER_BLOCK)
            sbuf[(cc + 1) & 1][t] = cvt8(a0, a1);
    }

    if (ATOMIC) {
        float* ob = dst + (size_t)b * NM * NK;
#pragma unroll
        for (int j = 0; j < PX_PER_THREAD; ++j) {
            const int m = px0 + j * THREADS + t;
            float* op = ob + (size_t)m * NK;
            atomicAdd(op + 0, acc[j].x);
            atomicAdd(op + 1, acc[j].y);
            atomicAdd(op + 2, acc[j].z);
            atomicAdd(op + 3, acc[j].w);
        }
    } else {
        // partial[chunk][b][m] — disjoint per block. NON-TEMPORAL: write-once
        // data must not allocate in L2/LLC (evicts rf + dirty poison lines).
        f32x4* pw = (f32x4*)dst + (size_t)(chunk * NBATCH + b) * NM;
#pragma unroll
        for (int j = 0; j < PX_PER_THREAD; ++j) {
            const int m = px0 + j * THREADS + t;
            const f32x4 v = {acc[j].x, acc[j].y, acc[j].z, acc[j].w};
            __builtin_nontemporal_store(v, pw + m);
        }
    }
}

// out[i] = sum over 8 chunk partials; i indexes float4 over [B*NM)
__global__ __launch_bounds__(256) void reduce_kernel(
    const f32x4* __restrict__ part, f32x4* __restrict__ out)
{
    const int i = blockIdx.x * 256 + threadIdx.x;
    const size_t stride = (size_t)NBATCH * NM;
    f32x4 a = __builtin_nontemporal_load(part + i);
#pragma unroll
    for (int c = 1; c < N_CHUNKS; ++c) {
        const f32x4 v = __builtin_nontemporal_load(part + c * stride + i);
        a += v;
    }
    out[i] = a;
}

extern "C" void kernel_launch(void* const* d_in, const int* in_sizes, int n_in,
                              void* d_out, int out_size, void* d_ws, size_t ws_size,
                              hipStream_t stream) {
    (void)in_sizes; (void)n_in;
    const float* rf = (const float*)d_in[0];
    const float* g  = (const float*)d_in[1];
    const float* pr = (const float*)d_in[2];
    const float* p  = (const float*)d_in[3];
    float* out = (float*)d_out;

    if (ws_size >= PART_BYTES) {
        das_kernel<false><<<NBLOCKS, THREADS, 0, stream>>>(rf, g, pr, p, (float*)d_ws);
        reduce_kernel<<<(NBATCH * NM) / 256, 256, 0, stream>>>((const f32x4*)d_ws,
                                                               (f32x4*)out);
    } else {
        (void)hipMemsetAsync(d_out, 0, (size_t)out_size * sizeof(float), stream);
        das_kernel<true><<<NBLOCKS, THREADS, 0, stream>>>(rf, g, pr, p, out);
    }
}